// Round 14
// baseline (129.762 us; speedup 1.0000x reference)
//
#include <hip/hip_runtime.h>

#define NN 10000
#define NE 640000
#define NB 313          // buckets of 32 nodes
#define RSTRIDE 2688    // slots per bucket (mean 2045, sigma~45)
#define EPB 1024        // edges per partition block
#define PBLK 625        // partition blocks (625*1024 == 640000 exactly)
#define G1B 1250        // gemm1 blocks (8 rows each)

__device__ __forceinline__ unsigned short f2bf(float x) {   // RNE
    unsigned u = __float_as_uint(x);
    u += 0x7FFFu + ((u >> 16) & 1u);
    return (unsigned short)(u >> 16);
}
__device__ __forceinline__ float bflo(unsigned u) { return __uint_as_float(u << 16); }
__device__ __forceinline__ float bfhi(unsigned u) { return __uint_as_float(u & 0xFFFF0000u); }

__device__ __forceinline__ void acc8w(float* acc, uint4 u, float w) {
    acc[0] += w * bflo(u.x); acc[1] += w * bfhi(u.x);
    acc[2] += w * bflo(u.y); acc[3] += w * bfhi(u.y);
    acc[4] += w * bflo(u.z); acc[5] += w * bfhi(u.z);
    acc[6] += w * bflo(u.w); acc[7] += w * bfhi(u.w);
}
__device__ __forceinline__ void acc8p(float* acc, uint4 u) {
    acc[0] += bflo(u.x); acc[1] += bfhi(u.x);
    acc[2] += bflo(u.y); acc[3] += bfhi(u.y);
    acc[4] += bflo(u.z); acc[5] += bfhi(u.z);
    acc[6] += bflo(u.w); acc[7] += bfhi(u.w);
}
__device__ __forceinline__ void acc4p(float* acc, uint2 u) {
    acc[0] += bflo(u.x); acc[1] += bfhi(u.x);
    acc[2] += bflo(u.y); acc[3] += bfhi(u.y);
}

struct SMpart {
    int hist[4][NB];        // per-wave private histograms
    int scanv[NB + 1];
    int wbase[4][NB];       // per-wave staging cursors
    int gbase[NB];
    unsigned stage[EPB];
};
struct SMbuild {
    int sbase[NB + 1];
    int hist32[4][32];      // per-wave private histograms
    int wcur32[4][32];      // per-wave placement cursors
    unsigned stage[RSTRIDE];
};
union SMu {
    SMpart p;
    SMbuild b;
    float xs[16][128];
};

__global__ void zero_kernel(int* __restrict__ cur) {
    if (threadIdx.x < NB) cur[threadIdx.x] = 0;
}

// ---- gemm1: 8 rows of Y = X[f32] @ W[128x128] -> bf16 (unscaled) ----
__device__ __forceinline__ void gemm1_block(const float* __restrict__ X,
                                            const float* __restrict__ W,
                                            unsigned short* __restrict__ Y,
                                            float (*xs)[128], int vb, int tid) {
    int row0 = vb * 8;
    for (int idx = tid; idx < 8 * 128; idx += 256) {
        int r = idx >> 7, k = idx & 127;
        xs[r][k] = X[(size_t)(row0 + r) * 128 + k];
    }
    __syncthreads();
    int ct = tid & 31, r = tid >> 5, c = ct * 4;
    float4 acc = make_float4(0.f, 0.f, 0.f, 0.f);
    #pragma unroll 8
    for (int k = 0; k < 128; ++k) {
        float xv = xs[r][k];
        float4 w = *reinterpret_cast<const float4*>(W + (size_t)k * 128 + c);
        acc.x += xv * w.x; acc.y += xv * w.y; acc.z += xv * w.z; acc.w += xv * w.w;
    }
    ushort4 o;
    o.x = f2bf(acc.x); o.y = f2bf(acc.y); o.z = f2bf(acc.z); o.w = f2bf(acc.w);
    *reinterpret_cast<ushort4*>(Y + (size_t)(row0 + r) * 128 + c) = o;
}

// ---- bf16-in GEMM; optional per-row isq prescale in f32 epilogue ----
template<int NOUTc, int ROWS, bool SCALE>
__device__ __forceinline__ void gemm_bf_block(const unsigned short* __restrict__ Xb,
                                              const float* __restrict__ W,
                                              const float* __restrict__ isqv,
                                              unsigned short* __restrict__ Y,
                                              float (*xs)[128], int vb, int tid) {
    int row0 = vb * ROWS;
    const unsigned* Xu = reinterpret_cast<const unsigned*>(Xb + (size_t)row0 * 128);
    for (int idx = tid; idx < ROWS * 64; idx += 256) {
        unsigned u = Xu[idx];
        int r = idx >> 6, kk = idx & 63;
        xs[r][kk * 2]     = bflo(u);
        xs[r][kk * 2 + 1] = bfhi(u);
    }
    __syncthreads();
    constexpr int COLT = NOUTc / 4;
    int ct = tid % COLT, r = tid / COLT, c = ct * 4;
    float4 acc = make_float4(0.f, 0.f, 0.f, 0.f);
    #pragma unroll 8
    for (int k = 0; k < 128; ++k) {
        float xv = xs[r][k];
        float4 w = *reinterpret_cast<const float4*>(W + (size_t)k * NOUTc + c);
        acc.x += xv * w.x; acc.y += xv * w.y; acc.z += xv * w.z; acc.w += xv * w.w;
    }
    int gr = row0 + r;
    if (SCALE) {
        float sc = isqv[gr];
        acc.x *= sc; acc.y *= sc; acc.z *= sc; acc.w *= sc;
    }
    ushort4 o;
    o.x = f2bf(acc.x); o.y = f2bf(acc.y); o.z = f2bf(acc.z); o.w = f2bf(acc.w);
    *reinterpret_cast<ushort4*>(Y + (size_t)gr * NOUTc + c) = o;
}

// ---- partition: one block of EPB=1024 edges -> bucketed records.
//      Per-wave private hist + cursors (no cross-wave LDS atomic contention).
__device__ __forceinline__ void partition_block(const int* __restrict__ src,
                                                const int* __restrict__ dst,
                                                int* __restrict__ bcur,
                                                unsigned* __restrict__ edge_part,
                                                SMpart& p, int bid, int tid) {
    int wv = tid >> 6;
    for (int i = tid; i < 4 * NB; i += 256) (&p.hist[0][0])[i] = 0;
    __syncthreads();
    int gi = bid * EPB + tid * 4;          // always in range (625*1024 == NE)
    int4 s4 = *reinterpret_cast<const int4*>(src + gi);
    int4 d4 = *reinterpret_cast<const int4*>(dst + gi);
    unsigned rec[4];
    rec[0] = ((unsigned)d4.x << 14) | (unsigned)s4.x;
    rec[1] = ((unsigned)d4.y << 14) | (unsigned)s4.y;
    rec[2] = ((unsigned)d4.z << 14) | (unsigned)s4.z;
    rec[3] = ((unsigned)d4.w << 14) | (unsigned)s4.w;
    #pragma unroll
    for (int k = 0; k < 4; ++k) atomicAdd(&p.hist[wv][rec[k] >> 19], 1);
    __syncthreads();
    if (tid < 64) {          // wave-0: scan totals, derive per-wave bases
        int carry = 0;
        for (int c = 0; c < NB; c += 64) {
            int idx = c + tid;
            int h0 = 0, h1 = 0, h2 = 0, h3 = 0, v = 0;
            if (idx < NB) {
                h0 = p.hist[0][idx]; h1 = p.hist[1][idx];
                h2 = p.hist[2][idx]; h3 = p.hist[3][idx];
                v = h0 + h1 + h2 + h3;
            }
            int incl = v;
            #pragma unroll
            for (int d = 1; d < 64; d <<= 1) {
                int t = __shfl_up(incl, d, 64);
                if (tid >= d) incl += t;
            }
            if (idx < NB) {
                int base = carry + incl - v;
                p.scanv[idx] = base;
                p.wbase[0][idx] = base;
                p.wbase[1][idx] = base + h0;
                p.wbase[2][idx] = base + h0 + h1;
                p.wbase[3][idx] = base + h0 + h1 + h2;
            }
            carry += __shfl(incl, 63, 64);
        }
        if (tid == 0) p.scanv[NB] = carry;
    }
    __syncthreads();
    for (int bb = tid; bb < NB; bb += 256) {
        int cntb = p.scanv[bb + 1] - p.scanv[bb];
        p.gbase[bb] = atomicAdd(&bcur[bb], cntb);
    }
    __syncthreads();
    #pragma unroll
    for (int k = 0; k < 4; ++k) {
        int bb = rec[k] >> 19;
        int pp = atomicAdd(&p.wbase[wv][bb], 1);
        p.stage[pp] = rec[k];
    }
    __syncthreads();
    for (int i = tid; i < EPB; i += 256) {
        unsigned r = p.stage[i];
        int bb = r >> 19;
        edge_part[bb * RSTRIDE + p.gbase[bb] + (i - p.scanv[bb])] = r;
    }
}

// ---- build: one bucket -> offs/inv_sqrt + node-sorted CSR (ushort src).
//      Per-wave private hist + cursors.
__device__ __forceinline__ void build_block(const unsigned* __restrict__ edge_part,
                                            const int* __restrict__ bcur,
                                            int* __restrict__ offs,
                                            float* __restrict__ inv_sqrt,
                                            unsigned short* __restrict__ edge_src,
                                            SMbuild& b, int bid, int tid) {
    int wv = tid >> 6;
    if (tid < 64) {
        int carry = 0;
        for (int c = 0; c < NB; c += 64) {
            int idx = c + tid;
            int v = (idx < NB) ? bcur[idx] : 0;
            int incl = v;
            #pragma unroll
            for (int d = 1; d < 64; d <<= 1) {
                int t = __shfl_up(incl, d, 64);
                if (tid >= d) incl += t;
            }
            if (idx < NB) b.sbase[idx] = carry + incl - v;
            carry += __shfl(incl, 63, 64);
        }
    }
    if (tid < 128) (&b.hist32[0][0])[tid] = 0;
    __syncthreads();
    int cnt = bcur[bid];
    int base = b.sbase[bid];
    const unsigned* part = edge_part + (size_t)bid * RSTRIDE;
    for (int k = tid; k < cnt; k += 256)
        atomicAdd(&b.hist32[wv][(part[k] >> 14) & 31], 1);
    __syncthreads();
    if (tid < 32) {
        int h0 = b.hist32[0][tid], h1 = b.hist32[1][tid];
        int h2 = b.hist32[2][tid], h3 = b.hist32[3][tid];
        int v = h0 + h1 + h2 + h3;
        int incl = v;
        #pragma unroll
        for (int d = 1; d < 32; d <<= 1) {
            int t = __shfl_up(incl, d, 32);
            if (tid >= d) incl += t;
        }
        int excl = incl - v;
        b.wcur32[0][tid] = excl;
        b.wcur32[1][tid] = excl + h0;
        b.wcur32[2][tid] = excl + h0 + h1;
        b.wcur32[3][tid] = excl + h0 + h1 + h2;
        int node = bid * 32 + tid;
        if (node < NN) {
            offs[node] = base + excl;
            inv_sqrt[node] = rsqrtf((float)(v + 1));
        }
        if (bid == NB - 1 && tid == 0) offs[NN] = base + cnt;
    }
    __syncthreads();
    for (int k = tid; k < cnt; k += 256) {
        unsigned r = part[k];
        int pp = atomicAdd(&b.wcur32[wv][(r >> 14) & 31], 1);
        b.stage[pp] = r & 0x3FFFu;
    }
    __syncthreads();
    for (int k = tid; k < cnt; k += 256)
        edge_src[base + k] = (unsigned short)b.stage[k];
}

// ======================= kernels =======================
__global__ __launch_bounds__(256) void part_gemm1_kernel(
        const int* __restrict__ src, const int* __restrict__ dst,
        int* __restrict__ bcur, unsigned* __restrict__ edge_part,
        const float* __restrict__ X, const float* __restrict__ W,
        unsigned short* __restrict__ Y) {
    __shared__ SMu sm;
    int tid = threadIdx.x;
    if (blockIdx.x >= PBLK) {
        gemm1_block(X, W, Y, sm.xs, blockIdx.x - PBLK, tid);
        return;
    }
    partition_block(src, dst, bcur, edge_part, sm.p, blockIdx.x, tid);
}

__global__ __launch_bounds__(256) void build_kernel(
        const unsigned* __restrict__ edge_part, const int* __restrict__ bcur,
        int* __restrict__ offs, float* __restrict__ inv_sqrt,
        unsigned short* __restrict__ edge_src) {
    __shared__ SMu sm;
    build_block(edge_part, bcur, offs, inv_sqrt, edge_src, sm.b,
                blockIdx.x, threadIdx.x);
}

// 128-ch aggregation. 2 waves/node (split chains); 4 groups of 16 lanes per
// wave, each group one edge (uint4 = 8 ch/lane); 16-edge unroll (4 gathers
// in flight/lane). PS: H rows pre-scaled by isq_src (no weight gather).
template<bool PS>
__global__ __launch_bounds__(128) void agg128_kernel(
        const unsigned short* __restrict__ H, const unsigned short* __restrict__ esrc,
        const int* __restrict__ offs, const float* __restrict__ isqv,
        const float* __restrict__ bias, uint4* __restrict__ Aout) {
    __shared__ float red[16][9];
    int node = blockIdx.x;
    int tid = threadIdx.x, lane = tid & 63, wv = tid >> 6;
    int l = lane & 15, g = lane >> 4;
    int s = offs[node], e = offs[node + 1];
    int deg = e - s;
    int half = ((deg >> 1) + 3) & ~3;
    int js = s + wv * half;
    if (js > e) js = e;
    int mid = s + half;
    int je = wv ? e : (mid < e ? mid : e);
    int colb = l * 8;
    float acc[8];
    #pragma unroll
    for (int i = 0; i < 8; ++i) acc[i] = 0.f;
    int j = js;
    for (; j + 16 <= je; j += 16) {
        int sA = esrc[j + g],      sB = esrc[j + 4 + g];
        int sC = esrc[j + 8 + g],  sD = esrc[j + 12 + g];
        uint4 a = *reinterpret_cast<const uint4*>(H + (size_t)sA * 128 + colb);
        uint4 b = *reinterpret_cast<const uint4*>(H + (size_t)sB * 128 + colb);
        uint4 c = *reinterpret_cast<const uint4*>(H + (size_t)sC * 128 + colb);
        uint4 d = *reinterpret_cast<const uint4*>(H + (size_t)sD * 128 + colb);
        if (PS) {
            acc8p(acc, a); acc8p(acc, b); acc8p(acc, c); acc8p(acc, d);
        } else {
            float wA = isqv[sA], wB = isqv[sB], wC = isqv[sC], wD = isqv[sD];
            acc8w(acc, a, wA); acc8w(acc, b, wB);
            acc8w(acc, c, wC); acc8w(acc, d, wD);
        }
    }
    for (; j + 4 <= je; j += 4) {
        int sA = esrc[j + g];
        uint4 a = *reinterpret_cast<const uint4*>(H + (size_t)sA * 128 + colb);
        if (PS) { acc8p(acc, a); }
        else    { acc8w(acc, a, isqv[sA]); }
    }
    int rem = je - j;
    if (g < rem) {
        int sA = esrc[j + g];
        uint4 a = *reinterpret_cast<const uint4*>(H + (size_t)sA * 128 + colb);
        if (PS) { acc8p(acc, a); }
        else    { acc8w(acc, a, isqv[sA]); }
    }
    #pragma unroll
    for (int i = 0; i < 8; ++i) {
        acc[i] += __shfl_down(acc[i], 32);
        acc[i] += __shfl_down(acc[i], 16);
    }
    if (wv == 1 && lane < 16) {
        #pragma unroll
        for (int i = 0; i < 8; ++i) red[l][i] = acc[i];
    }
    __syncthreads();
    if (wv == 0 && lane < 16) {
        float isq = isqv[node];
        uint4 uv = *reinterpret_cast<const uint4*>(H + (size_t)node * 128 + colb);
        float sv[8] = { bflo(uv.x), bfhi(uv.x), bflo(uv.y), bfhi(uv.y),
                        bflo(uv.z), bfhi(uv.z), bflo(uv.w), bfhi(uv.w) };
        float o[8];
        #pragma unroll
        for (int i = 0; i < 8; ++i) {
            float a = acc[i] + red[l][i];
            a += PS ? sv[i] : isq * sv[i];
            o[i] = fmaxf(isq * a + bias[colb + i], 0.f);
        }
        uint4 ov;
        ov.x = (unsigned)f2bf(o[0]) | ((unsigned)f2bf(o[1]) << 16);
        ov.y = (unsigned)f2bf(o[2]) | ((unsigned)f2bf(o[3]) << 16);
        ov.z = (unsigned)f2bf(o[4]) | ((unsigned)f2bf(o[5]) << 16);
        ov.w = (unsigned)f2bf(o[6]) | ((unsigned)f2bf(o[7]) << 16);
        Aout[(size_t)node * 16 + l] = ov;
    }
}

// 64-ch final aggregation (prescaled H), f32 out, no relu
__global__ __launch_bounds__(128) void agg64_kernel(
        const unsigned short* __restrict__ H, const unsigned short* __restrict__ esrc,
        const int* __restrict__ offs, const float* __restrict__ isqv,
        const float* __restrict__ bias, float* __restrict__ out) {
    __shared__ float red[16][5];
    int node = blockIdx.x;
    int tid = threadIdx.x, lane = tid & 63, wv = tid >> 6;
    int l = lane & 15, g = lane >> 4;
    int s = offs[node], e = offs[node + 1];
    int deg = e - s;
    int half = ((deg >> 1) + 3) & ~3;
    int js = s + wv * half;
    if (js > e) js = e;
    int mid = s + half;
    int je = wv ? e : (mid < e ? mid : e);
    int colb = l * 4;
    float acc[4] = {0.f, 0.f, 0.f, 0.f};
    int j = js;
    for (; j + 16 <= je; j += 16) {
        int s0 = esrc[j + g],      s1 = esrc[j + 4 + g];
        int s2 = esrc[j + 8 + g],  s3 = esrc[j + 12 + g];
        uint2 a0 = *reinterpret_cast<const uint2*>(H + (size_t)s0 * 64 + colb);
        uint2 a1 = *reinterpret_cast<const uint2*>(H + (size_t)s1 * 64 + colb);
        uint2 a2 = *reinterpret_cast<const uint2*>(H + (size_t)s2 * 64 + colb);
        uint2 a3 = *reinterpret_cast<const uint2*>(H + (size_t)s3 * 64 + colb);
        acc4p(acc, a0); acc4p(acc, a1); acc4p(acc, a2); acc4p(acc, a3);
    }
    for (; j + 4 <= je; j += 4) {
        int s0 = esrc[j + g];
        uint2 a0 = *reinterpret_cast<const uint2*>(H + (size_t)s0 * 64 + colb);
        acc4p(acc, a0);
    }
    int rem = je - j;
    if (g < rem) {
        int s0 = esrc[j + g];
        uint2 a0 = *reinterpret_cast<const uint2*>(H + (size_t)s0 * 64 + colb);
        acc4p(acc, a0);
    }
    #pragma unroll
    for (int i = 0; i < 4; ++i) {
        acc[i] += __shfl_down(acc[i], 32);
        acc[i] += __shfl_down(acc[i], 16);
    }
    if (wv == 1 && lane < 16) {
        #pragma unroll
        for (int i = 0; i < 4; ++i) red[l][i] = acc[i];
    }
    __syncthreads();
    if (wv == 0 && lane < 16) {
        float isq = isqv[node];
        uint2 uv = *reinterpret_cast<const uint2*>(H + (size_t)node * 64 + colb);
        float sv[4] = { bflo(uv.x), bfhi(uv.x), bflo(uv.y), bfhi(uv.y) };
        float4 ov;
        ov.x = isq * (acc[0] + red[l][0] + sv[0]) + bias[colb];
        ov.y = isq * (acc[1] + red[l][1] + sv[1]) + bias[colb + 1];
        ov.z = isq * (acc[2] + red[l][2] + sv[2]) + bias[colb + 2];
        ov.w = isq * (acc[3] + red[l][3] + sv[3]) + bias[colb + 3];
        *reinterpret_cast<float4*>(out + (size_t)node * 64 + colb) = ov;
    }
}

template<int N, bool SCALE>
__global__ __launch_bounds__(256) void gemm_bf_kernel(
        const unsigned short* __restrict__ X, const float* __restrict__ W,
        const float* __restrict__ isqv, unsigned short* __restrict__ Y) {
    __shared__ SMu sm;
    gemm_bf_block<N, 256 / (N / 4), SCALE>(X, W, isqv, Y, sm.xs,
                                           blockIdx.x, threadIdx.x);
}

extern "C" void kernel_launch(void* const* d_in, const int* in_sizes, int n_in,
                              void* d_out, int out_size, void* d_ws, size_t ws_size,
                              hipStream_t stream) {
    const float* x  = (const float*)d_in[0];
    const int*   ei = (const int*)d_in[1];
    const float* W1 = (const float*)d_in[2];
    const float* b1 = (const float*)d_in[3];
    const float* W2 = (const float*)d_in[4];
    const float* b2 = (const float*)d_in[5];
    const float* W3 = (const float*)d_in[6];
    const float* b3 = (const float*)d_in[7];
    float* out = (float*)d_out;

    const int* src = ei;
    const int* dst = ei + NE;

    char* ws = (char*)d_ws;
    int*            bcur      = (int*)(ws);                        // 1,252 B
    float*          inv_sqrt  = (float*)(ws + 4096);               // 40,000 B
    int*            offs      = (int*)(ws + 45056);                // 40,004 B
    unsigned*       edge_part = (unsigned*)(ws + 86016);           // 3,365,376 B
    unsigned short* edge_src  = (unsigned short*)(ws + 3451392);   // 1,280,000 B
    unsigned short* T1        = (unsigned short*)(ws + 6011392);   // 2,560,000 B
    unsigned short* A         = (unsigned short*)(ws + 8571392);   // 2,560,000 B
    unsigned short* T2        = (unsigned short*)edge_part;        // alias (dead after build)
    unsigned short* T3        = T1;                                // alias (dead after agg1)

    zero_kernel<<<1, 320, 0, stream>>>(bcur);
    part_gemm1_kernel<<<PBLK + G1B, 256, 0, stream>>>(src, dst, bcur, edge_part,
                                                      x, W1, T1);
    build_kernel<<<NB, 256, 0, stream>>>(edge_part, bcur, offs, inv_sqrt, edge_src);
    agg128_kernel<false><<<NN, 128, 0, stream>>>(T1, edge_src, offs, inv_sqrt, b1,
                                                 (uint4*)A);
    gemm_bf_kernel<128, true><<<NN / 8, 256, 0, stream>>>(A, W2, inv_sqrt, T2);
    agg128_kernel<true><<<NN, 128, 0, stream>>>(T2, edge_src, offs, inv_sqrt, b2,
                                                (uint4*)A);
    gemm_bf_kernel<64, true><<<NN / 16, 256, 0, stream>>>(A, W3, inv_sqrt, T3);
    agg64_kernel<<<NN, 128, 0, stream>>>(T3, edge_src, offs, inv_sqrt, b3, out);
}

// Round 15
// 120.870 us; speedup vs baseline: 1.0736x; 1.0736x over previous
//
#include <hip/hip_runtime.h>

#define NN 10000
#define NE 640000
#define NB 313          // buckets of 32 nodes; also # partition blocks
#define RSTRIDE 2688    // slots per bucket (mean 2045, sigma~45)
#define EPB 2048        // edges per partition block
#define G1B 1250        // gemm1 blocks (8 rows each)

__device__ __forceinline__ unsigned short f2bf(float x) {   // RNE
    unsigned u = __float_as_uint(x);
    u += 0x7FFFu + ((u >> 16) & 1u);
    return (unsigned short)(u >> 16);
}
__device__ __forceinline__ float bflo(unsigned u) { return __uint_as_float(u << 16); }
__device__ __forceinline__ float bfhi(unsigned u) { return __uint_as_float(u & 0xFFFF0000u); }

__device__ __forceinline__ void acc8w(float* acc, uint4 u, float w) {
    acc[0] += w * bflo(u.x); acc[1] += w * bfhi(u.x);
    acc[2] += w * bflo(u.y); acc[3] += w * bfhi(u.y);
    acc[4] += w * bflo(u.z); acc[5] += w * bfhi(u.z);
    acc[6] += w * bflo(u.w); acc[7] += w * bfhi(u.w);
}
__device__ __forceinline__ void acc8p(float* acc, uint4 u) {
    acc[0] += bflo(u.x); acc[1] += bfhi(u.x);
    acc[2] += bflo(u.y); acc[3] += bfhi(u.y);
    acc[4] += bflo(u.z); acc[5] += bfhi(u.z);
    acc[6] += bflo(u.w); acc[7] += bfhi(u.w);
}
__device__ __forceinline__ void acc4p(float* acc, uint2 u) {
    acc[0] += bflo(u.x); acc[1] += bfhi(u.x);
    acc[2] += bflo(u.y); acc[3] += bfhi(u.y);
}

struct SMpart { int hist[NB]; int scanv[NB + 1]; int gbase[NB]; int lcur[NB];
                unsigned stage[EPB]; };
struct SMbuild { int sbase[NB + 1]; int hist32[32]; int cur32[32];
                 unsigned stage[RSTRIDE]; };
union SMu {
    SMpart p;
    SMbuild b;
    float xs[16][128];
};

__global__ void zero_kernel(int* __restrict__ cur) {
    if (threadIdx.x < NB) cur[threadIdx.x] = 0;
}

// ---- gemm1: 8 rows of Y = X[f32] @ W[128x128] -> bf16 (unscaled) ----
__device__ __forceinline__ void gemm1_block(const float* __restrict__ X,
                                            const float* __restrict__ W,
                                            unsigned short* __restrict__ Y,
                                            float (*xs)[128], int vb, int tid) {
    int row0 = vb * 8;
    for (int idx = tid; idx < 8 * 128; idx += 256) {
        int r = idx >> 7, k = idx & 127;
        xs[r][k] = X[(size_t)(row0 + r) * 128 + k];
    }
    __syncthreads();
    int ct = tid & 31, r = tid >> 5, c = ct * 4;
    float4 acc = make_float4(0.f, 0.f, 0.f, 0.f);
    #pragma unroll 8
    for (int k = 0; k < 128; ++k) {
        float xv = xs[r][k];
        float4 w = *reinterpret_cast<const float4*>(W + (size_t)k * 128 + c);
        acc.x += xv * w.x; acc.y += xv * w.y; acc.z += xv * w.z; acc.w += xv * w.w;
    }
    ushort4 o;
    o.x = f2bf(acc.x); o.y = f2bf(acc.y); o.z = f2bf(acc.z); o.w = f2bf(acc.w);
    *reinterpret_cast<ushort4*>(Y + (size_t)(row0 + r) * 128 + c) = o;
}

// ---- bf16-in GEMM; optional per-row isq prescale in f32 epilogue ----
template<int NOUTc, int ROWS, bool SCALE>
__device__ __forceinline__ void gemm_bf_block(const unsigned short* __restrict__ Xb,
                                              const float* __restrict__ W,
                                              const float* __restrict__ isqv,
                                              unsigned short* __restrict__ Y,
                                              float (*xs)[128], int vb, int tid) {
    int row0 = vb * ROWS;
    const unsigned* Xu = reinterpret_cast<const unsigned*>(Xb + (size_t)row0 * 128);
    for (int idx = tid; idx < ROWS * 64; idx += 256) {
        unsigned u = Xu[idx];
        int r = idx >> 6, kk = idx & 63;
        xs[r][kk * 2]     = bflo(u);
        xs[r][kk * 2 + 1] = bfhi(u);
    }
    __syncthreads();
    constexpr int COLT = NOUTc / 4;
    int ct = tid % COLT, r = tid / COLT, c = ct * 4;
    float4 acc = make_float4(0.f, 0.f, 0.f, 0.f);
    #pragma unroll 8
    for (int k = 0; k < 128; ++k) {
        float xv = xs[r][k];
        float4 w = *reinterpret_cast<const float4*>(W + (size_t)k * NOUTc + c);
        acc.x += xv * w.x; acc.y += xv * w.y; acc.z += xv * w.z; acc.w += xv * w.w;
    }
    int gr = row0 + r;
    if (SCALE) {
        float sc = isqv[gr];
        acc.x *= sc; acc.y *= sc; acc.z *= sc; acc.w *= sc;
    }
    ushort4 o;
    o.x = f2bf(acc.x); o.y = f2bf(acc.y); o.z = f2bf(acc.z); o.w = f2bf(acc.w);
    *reinterpret_cast<ushort4*>(Y + (size_t)gr * NOUTc + c) = o;
}

// ---- partition: one block of EPB edges -> bucketed records ----
__device__ __forceinline__ void partition_block(const int* __restrict__ src,
                                                const int* __restrict__ dst,
                                                int* __restrict__ bcur,
                                                unsigned* __restrict__ edge_part,
                                                SMpart& p, int bid, int tid) {
    for (int i = tid; i < NB; i += 256) p.hist[i] = 0;
    __syncthreads();
    int gi = bid * EPB + tid * 8;
    unsigned rec[8];
    bool act = gi < NE;
    if (act) {
        int4 s0 = *reinterpret_cast<const int4*>(src + gi);
        int4 s1 = *reinterpret_cast<const int4*>(src + gi + 4);
        int4 d0 = *reinterpret_cast<const int4*>(dst + gi);
        int4 d1 = *reinterpret_cast<const int4*>(dst + gi + 4);
        rec[0] = ((unsigned)d0.x << 14) | (unsigned)s0.x;
        rec[1] = ((unsigned)d0.y << 14) | (unsigned)s0.y;
        rec[2] = ((unsigned)d0.z << 14) | (unsigned)s0.z;
        rec[3] = ((unsigned)d0.w << 14) | (unsigned)s0.w;
        rec[4] = ((unsigned)d1.x << 14) | (unsigned)s1.x;
        rec[5] = ((unsigned)d1.y << 14) | (unsigned)s1.y;
        rec[6] = ((unsigned)d1.z << 14) | (unsigned)s1.z;
        rec[7] = ((unsigned)d1.w << 14) | (unsigned)s1.w;
        #pragma unroll
        for (int k = 0; k < 8; ++k) atomicAdd(&p.hist[rec[k] >> 19], 1);
    }
    __syncthreads();
    if (tid < 64) {          // wave-0 exclusive scan of hist
        int carry = 0;
        for (int c = 0; c < NB; c += 64) {
            int idx = c + tid;
            int v = (idx < NB) ? p.hist[idx] : 0;
            int incl = v;
            #pragma unroll
            for (int d = 1; d < 64; d <<= 1) {
                int t = __shfl_up(incl, d, 64);
                if (tid >= d) incl += t;
            }
            if (idx < NB) p.scanv[idx] = carry + incl - v;
            carry += __shfl(incl, 63, 64);
        }
        if (tid == 0) p.scanv[NB] = carry;
    }
    __syncthreads();
    for (int bb = tid; bb < NB; bb += 256) {
        p.gbase[bb] = atomicAdd(&bcur[bb], p.hist[bb]);
        p.lcur[bb]  = p.scanv[bb];
    }
    __syncthreads();
    if (act) {
        #pragma unroll
        for (int k = 0; k < 8; ++k) {
            int bb = rec[k] >> 19;
            int pp = atomicAdd(&p.lcur[bb], 1);
            p.stage[pp] = rec[k];
        }
    }
    __syncthreads();
    int tot = p.scanv[NB];
    for (int i = tid; i < tot; i += 256) {
        unsigned r = p.stage[i];
        int bb = r >> 19;
        edge_part[bb * RSTRIDE + p.gbase[bb] + (i - p.scanv[bb])] = r;
    }
}

// ---- build: one bucket -> offs/inv_sqrt + node-sorted CSR (ushort src) ----
__device__ __forceinline__ void build_block(const unsigned* __restrict__ edge_part,
                                            const int* __restrict__ bcur,
                                            int* __restrict__ offs,
                                            float* __restrict__ inv_sqrt,
                                            unsigned short* __restrict__ edge_src,
                                            SMbuild& b, int bid, int tid) {
    if (tid < 64) {
        int carry = 0;
        for (int c = 0; c < NB; c += 64) {
            int idx = c + tid;
            int v = (idx < NB) ? bcur[idx] : 0;
            int incl = v;
            #pragma unroll
            for (int d = 1; d < 64; d <<= 1) {
                int t = __shfl_up(incl, d, 64);
                if (tid >= d) incl += t;
            }
            if (idx < NB) b.sbase[idx] = carry + incl - v;
            carry += __shfl(incl, 63, 64);
        }
    }
    if (tid < 32) b.hist32[tid] = 0;
    __syncthreads();
    int cnt = bcur[bid];
    int base = b.sbase[bid];
    const unsigned* part = edge_part + (size_t)bid * RSTRIDE;
    for (int k = tid; k < cnt; k += 256)
        atomicAdd(&b.hist32[(part[k] >> 14) & 31], 1);
    __syncthreads();
    if (tid < 32) {
        int v = b.hist32[tid];
        int incl = v;
        #pragma unroll
        for (int d = 1; d < 32; d <<= 1) {
            int t = __shfl_up(incl, d, 32);
            if (tid >= d) incl += t;
        }
        int excl = incl - v;
        b.cur32[tid] = excl;
        int node = bid * 32 + tid;
        if (node < NN) {
            offs[node] = base + excl;
            inv_sqrt[node] = rsqrtf((float)(v + 1));
        }
        if (bid == NB - 1 && tid == 0) offs[NN] = base + cnt;
    }
    __syncthreads();
    for (int k = tid; k < cnt; k += 256) {
        unsigned r = part[k];
        int pp = atomicAdd(&b.cur32[(r >> 14) & 31], 1);
        b.stage[pp] = r & 0x3FFFu;
    }
    __syncthreads();
    for (int k = tid; k < cnt; k += 256)
        edge_src[base + k] = (unsigned short)b.stage[k];
}

// ======================= kernels =======================
__global__ __launch_bounds__(256) void part_gemm1_kernel(
        const int* __restrict__ src, const int* __restrict__ dst,
        int* __restrict__ bcur, unsigned* __restrict__ edge_part,
        const float* __restrict__ X, const float* __restrict__ W,
        unsigned short* __restrict__ Y) {
    __shared__ SMu sm;
    int tid = threadIdx.x;
    if (blockIdx.x >= NB) {
        gemm1_block(X, W, Y, sm.xs, blockIdx.x - NB, tid);
        return;
    }
    partition_block(src, dst, bcur, edge_part, sm.p, blockIdx.x, tid);
}

__global__ __launch_bounds__(256) void build_kernel(
        const unsigned* __restrict__ edge_part, const int* __restrict__ bcur,
        int* __restrict__ offs, float* __restrict__ inv_sqrt,
        unsigned short* __restrict__ edge_src) {
    __shared__ SMu sm;
    build_block(edge_part, bcur, offs, inv_sqrt, edge_src, sm.b,
                blockIdx.x, threadIdx.x);
}

// 128-ch aggregation. 2 waves/node (split chains); 4 groups of 16 lanes per
// wave, each group one edge (uint4 = 8 ch/lane); 16-edge unroll (4 gathers
// in flight/lane). PS: H rows pre-scaled by isq_src (no weight gather).
template<bool PS>
__global__ __launch_bounds__(128) void agg128_kernel(
        const unsigned short* __restrict__ H, const unsigned short* __restrict__ esrc,
        const int* __restrict__ offs, const float* __restrict__ isqv,
        const float* __restrict__ bias, uint4* __restrict__ Aout) {
    __shared__ float red[16][9];
    int node = blockIdx.x;
    int tid = threadIdx.x, lane = tid & 63, wv = tid >> 6;
    int l = lane & 15, g = lane >> 4;
    int s = offs[node], e = offs[node + 1];
    int deg = e - s;
    int half = ((deg >> 1) + 3) & ~3;
    int js = s + wv * half;
    if (js > e) js = e;
    int mid = s + half;
    int je = wv ? e : (mid < e ? mid : e);
    int colb = l * 8;
    float acc[8];
    #pragma unroll
    for (int i = 0; i < 8; ++i) acc[i] = 0.f;
    int j = js;
    for (; j + 16 <= je; j += 16) {
        int sA = esrc[j + g],      sB = esrc[j + 4 + g];
        int sC = esrc[j + 8 + g],  sD = esrc[j + 12 + g];
        uint4 a = *reinterpret_cast<const uint4*>(H + (size_t)sA * 128 + colb);
        uint4 b = *reinterpret_cast<const uint4*>(H + (size_t)sB * 128 + colb);
        uint4 c = *reinterpret_cast<const uint4*>(H + (size_t)sC * 128 + colb);
        uint4 d = *reinterpret_cast<const uint4*>(H + (size_t)sD * 128 + colb);
        if (PS) {
            acc8p(acc, a); acc8p(acc, b); acc8p(acc, c); acc8p(acc, d);
        } else {
            float wA = isqv[sA], wB = isqv[sB], wC = isqv[sC], wD = isqv[sD];
            acc8w(acc, a, wA); acc8w(acc, b, wB);
            acc8w(acc, c, wC); acc8w(acc, d, wD);
        }
    }
    for (; j + 4 <= je; j += 4) {
        int sA = esrc[j + g];
        uint4 a = *reinterpret_cast<const uint4*>(H + (size_t)sA * 128 + colb);
        if (PS) { acc8p(acc, a); }
        else    { acc8w(acc, a, isqv[sA]); }
    }
    int rem = je - j;
    if (g < rem) {
        int sA = esrc[j + g];
        uint4 a = *reinterpret_cast<const uint4*>(H + (size_t)sA * 128 + colb);
        if (PS) { acc8p(acc, a); }
        else    { acc8w(acc, a, isqv[sA]); }
    }
    #pragma unroll
    for (int i = 0; i < 8; ++i) {
        acc[i] += __shfl_down(acc[i], 32);
        acc[i] += __shfl_down(acc[i], 16);
    }
    if (wv == 1 && lane < 16) {
        #pragma unroll
        for (int i = 0; i < 8; ++i) red[l][i] = acc[i];
    }
    __syncthreads();
    if (wv == 0 && lane < 16) {
        float isq = isqv[node];
        uint4 uv = *reinterpret_cast<const uint4*>(H + (size_t)node * 128 + colb);
        float sv[8] = { bflo(uv.x), bfhi(uv.x), bflo(uv.y), bfhi(uv.y),
                        bflo(uv.z), bfhi(uv.z), bflo(uv.w), bfhi(uv.w) };
        float o[8];
        #pragma unroll
        for (int i = 0; i < 8; ++i) {
            float a = acc[i] + red[l][i];
            a += PS ? sv[i] : isq * sv[i];
            o[i] = fmaxf(isq * a + bias[colb + i], 0.f);
        }
        uint4 ov;
        ov.x = (unsigned)f2bf(o[0]) | ((unsigned)f2bf(o[1]) << 16);
        ov.y = (unsigned)f2bf(o[2]) | ((unsigned)f2bf(o[3]) << 16);
        ov.z = (unsigned)f2bf(o[4]) | ((unsigned)f2bf(o[5]) << 16);
        ov.w = (unsigned)f2bf(o[6]) | ((unsigned)f2bf(o[7]) << 16);
        Aout[(size_t)node * 16 + l] = ov;
    }
}

// 64-ch final aggregation (prescaled H), f32 out, no relu
__global__ __launch_bounds__(128) void agg64_kernel(
        const unsigned short* __restrict__ H, const unsigned short* __restrict__ esrc,
        const int* __restrict__ offs, const float* __restrict__ isqv,
        const float* __restrict__ bias, float* __restrict__ out) {
    __shared__ float red[16][5];
    int node = blockIdx.x;
    int tid = threadIdx.x, lane = tid & 63, wv = tid >> 6;
    int l = lane & 15, g = lane >> 4;
    int s = offs[node], e = offs[node + 1];
    int deg = e - s;
    int half = ((deg >> 1) + 3) & ~3;
    int js = s + wv * half;
    if (js > e) js = e;
    int mid = s + half;
    int je = wv ? e : (mid < e ? mid : e);
    int colb = l * 4;
    float acc[4] = {0.f, 0.f, 0.f, 0.f};
    int j = js;
    for (; j + 16 <= je; j += 16) {
        int s0 = esrc[j + g],      s1 = esrc[j + 4 + g];
        int s2 = esrc[j + 8 + g],  s3 = esrc[j + 12 + g];
        uint2 a0 = *reinterpret_cast<const uint2*>(H + (size_t)s0 * 64 + colb);
        uint2 a1 = *reinterpret_cast<const uint2*>(H + (size_t)s1 * 64 + colb);
        uint2 a2 = *reinterpret_cast<const uint2*>(H + (size_t)s2 * 64 + colb);
        uint2 a3 = *reinterpret_cast<const uint2*>(H + (size_t)s3 * 64 + colb);
        acc4p(acc, a0); acc4p(acc, a1); acc4p(acc, a2); acc4p(acc, a3);
    }
    for (; j + 4 <= je; j += 4) {
        int s0 = esrc[j + g];
        uint2 a0 = *reinterpret_cast<const uint2*>(H + (size_t)s0 * 64 + colb);
        acc4p(acc, a0);
    }
    int rem = je - j;
    if (g < rem) {
        int s0 = esrc[j + g];
        uint2 a0 = *reinterpret_cast<const uint2*>(H + (size_t)s0 * 64 + colb);
        acc4p(acc, a0);
    }
    #pragma unroll
    for (int i = 0; i < 4; ++i) {
        acc[i] += __shfl_down(acc[i], 32);
        acc[i] += __shfl_down(acc[i], 16);
    }
    if (wv == 1 && lane < 16) {
        #pragma unroll
        for (int i = 0; i < 4; ++i) red[l][i] = acc[i];
    }
    __syncthreads();
    if (wv == 0 && lane < 16) {
        float isq = isqv[node];
        uint2 uv = *reinterpret_cast<const uint2*>(H + (size_t)node * 64 + colb);
        float sv[4] = { bflo(uv.x), bfhi(uv.x), bflo(uv.y), bfhi(uv.y) };
        float4 ov;
        ov.x = isq * (acc[0] + red[l][0] + sv[0]) + bias[colb];
        ov.y = isq * (acc[1] + red[l][1] + sv[1]) + bias[colb + 1];
        ov.z = isq * (acc[2] + red[l][2] + sv[2]) + bias[colb + 2];
        ov.w = isq * (acc[3] + red[l][3] + sv[3]) + bias[colb + 3];
        *reinterpret_cast<float4*>(out + (size_t)node * 64 + colb) = ov;
    }
}

template<int N, bool SCALE>
__global__ __launch_bounds__(256) void gemm_bf_kernel(
        const unsigned short* __restrict__ X, const float* __restrict__ W,
        const float* __restrict__ isqv, unsigned short* __restrict__ Y) {
    __shared__ SMu sm;
    gemm_bf_block<N, 256 / (N / 4), SCALE>(X, W, isqv, Y, sm.xs,
                                           blockIdx.x, threadIdx.x);
}

extern "C" void kernel_launch(void* const* d_in, const int* in_sizes, int n_in,
                              void* d_out, int out_size, void* d_ws, size_t ws_size,
                              hipStream_t stream) {
    const float* x  = (const float*)d_in[0];
    const int*   ei = (const int*)d_in[1];
    const float* W1 = (const float*)d_in[2];
    const float* b1 = (const float*)d_in[3];
    const float* W2 = (const float*)d_in[4];
    const float* b2 = (const float*)d_in[5];
    const float* W3 = (const float*)d_in[6];
    const float* b3 = (const float*)d_in[7];
    float* out = (float*)d_out;

    const int* src = ei;
    const int* dst = ei + NE;

    char* ws = (char*)d_ws;
    int*            bcur      = (int*)(ws);                        // 1,252 B
    float*          inv_sqrt  = (float*)(ws + 4096);               // 40,000 B
    int*            offs      = (int*)(ws + 45056);                // 40,004 B
    unsigned*       edge_part = (unsigned*)(ws + 86016);           // 3,365,376 B
    unsigned short* edge_src  = (unsigned short*)(ws + 3451392);   // 1,280,000 B
    unsigned short* T1        = (unsigned short*)(ws + 6011392);   // 2,560,000 B
    unsigned short* A         = (unsigned short*)(ws + 8571392);   // 2,560,000 B
    unsigned short* T2        = (unsigned short*)edge_part;        // alias (dead after build)
    unsigned short* T3        = T1;                                // alias (dead after agg1)

    zero_kernel<<<1, 320, 0, stream>>>(bcur);
    part_gemm1_kernel<<<NB + G1B, 256, 0, stream>>>(src, dst, bcur, edge_part,
                                                    x, W1, T1);
    build_kernel<<<NB, 256, 0, stream>>>(edge_part, bcur, offs, inv_sqrt, edge_src);
    agg128_kernel<false><<<NN, 128, 0, stream>>>(T1, edge_src, offs, inv_sqrt, b1,
                                                 (uint4*)A);
    gemm_bf_kernel<128, true><<<NN / 8, 256, 0, stream>>>(A, W2, inv_sqrt, T2);
    agg128_kernel<true><<<NN, 128, 0, stream>>>(T2, edge_src, offs, inv_sqrt, b2,
                                                (uint4*)A);
    gemm_bf_kernel<64, true><<<NN / 16, 256, 0, stream>>>(A, W3, inv_sqrt, T3);
    agg64_kernel<<<NN, 128, 0, stream>>>(T3, edge_src, offs, inv_sqrt, b3, out);
}